// Round 4
// baseline (35078.748 us; speedup 1.0000x reference)
//
#include <hip/hip_runtime.h>
#include <math.h>

#define B_    128
#define T_    256
#define DIM_  512
#define HID_  1024
#define OUT_  512
#define TAG_  64
#define K3_   3072
#define NWG_  96
#define CK_   128   // K-chunk

typedef float f32x4 __attribute__((ext_vector_type(4)));
typedef short bf16x8 __attribute__((ext_vector_type(8)));

#define MFMA(a,b,c) __builtin_amdgcn_mfma_f32_16x16x32_bf16(a,b,c,0,0,0)

typedef __attribute__((address_space(3))) void       lds_void_t;
typedef __attribute__((address_space(1))) const void gbl_cvoid_t;
#define GLOAD_LDS16(g, l) __builtin_amdgcn_global_load_lds((gbl_cvoid_t*)(g), (lds_void_t*)(l), 16, 0, 0)

// LDS layout (bytes): A dbuf 2x32768 at 0, B dbuf 2x8192 at 65536. total 81920.
#define AOFF0 0
#define AOFF1 32768
#define BOFF0 65536
#define BOFF1 73728

__device__ __forceinline__ unsigned short f2b(float f){
    unsigned int u = __float_as_uint(f);
    u = (u + 0x7fffu + ((u >> 16) & 1u)) >> 16;   // RNE
    return (unsigned short)u;
}
__device__ __forceinline__ float hardsig(float x){
    return fminf(fmaxf(0.2f*x + 0.5f, 0.f), 1.f);
}
__device__ __forceinline__ bf16x8 ld8f(const float* p){
    float4 a = *(const float4*)p;
    float4 b = *(const float4*)(p + 4);
    bf16x8 r;
    r[0]=(short)f2b(a.x); r[1]=(short)f2b(a.y); r[2]=(short)f2b(a.z); r[3]=(short)f2b(a.w);
    r[4]=(short)f2b(b.x); r[5]=(short)f2b(b.y); r[6]=(short)f2b(b.z); r[7]=(short)f2b(b.w);
    return r;
}

// ---- distributed-flag grid barrier: relaxed spins, one fence each side ----
__device__ __forceinline__ void gsync(unsigned* flags, unsigned gen, int wg, int tid){
    __syncthreads();
    __threadfence();   // release: make prior global writes visible (agent scope)
    if (tid == 0)
        __hip_atomic_store(&flags[wg], gen, __ATOMIC_RELAXED, __HIP_MEMORY_SCOPE_AGENT);
    if (wg == 0){
        if (tid < NWG_){
            while (__hip_atomic_load(&flags[tid], __ATOMIC_RELAXED, __HIP_MEMORY_SCOPE_AGENT) != gen)
                __builtin_amdgcn_s_sleep(2);
        }
        __syncthreads();
        if (tid == 0){
            __threadfence();   // order arrive-loads before go-store
            __hip_atomic_store(&flags[NWG_], gen, __ATOMIC_RELAXED, __HIP_MEMORY_SCOPE_AGENT);
        }
    } else {
        if (tid == 0){
            while (__hip_atomic_load(&flags[NWG_], __ATOMIC_RELAXED, __HIP_MEMORY_SCOPE_AGENT) != gen)
                __builtin_amdgcn_s_sleep(2);
        }
    }
    __syncthreads();
    __threadfence();   // acquire: invalidate stale cache before reading others' data
}

// ---- staging helpers ----
// LDS A layout: rows 0..127 x 128 K bf16 (256B/row), swizzle: 16B-unit k16 XOR (row&7).
// global_load_lds writes linearly (instr i covers rows i*4..i*4+3), so the SOURCE
// address is pre-swizzled; ds_read applies the same XOR. (both-sides-or-neither)
__device__ __forceinline__ void stage_act(
    char* smem, int off, int wv, int lane,
    const unsigned short* act, int stride, int k0)
{
    const int hi = lane >> 4, l15 = lane & 15;
    #pragma unroll
    for (int j = 0; j < 4; ++j){
        const int i   = wv*4 + j;          // instr 0..31
        const int row = i*4 + hi;          // 0..127
        const int k16 = l15 ^ (row & 7);
        const unsigned short* src = act + (size_t)row*stride + k0 + k16*8;
        GLOAD_LDS16(src, smem + off + i*1024);
    }
}
__device__ __forceinline__ void stage_act_f32(
    char* smem, int off, int wv, int lane,
    const float* act, int stride, int k0)
{
    const int hi = lane >> 4, l15 = lane & 15;
    #pragma unroll
    for (int j = 0; j < 4; ++j){
        const int i   = wv*4 + j;
        const int row = i*4 + hi;
        const int k16 = l15 ^ (row & 7);
        const float* src = act + (size_t)row*stride + k0 + k16*8;
        bf16x8 v = ld8f(src);
        *(bf16x8*)(smem + off + i*1024 + lane*16) = v;
    }
}
// B: 32 cols x 128 K, same swizzle on local col. 8 instrs, one per wave.
__device__ __forceinline__ void stage_wgt(
    char* smem, int off, int wv, int lane,
    const unsigned short* colbase, int stride, int kloc)
{
    const int col = wv*4 + (lane >> 4);    // local col 0..31
    const int k16 = (lane & 15) ^ (col & 7);
    const unsigned short* src = colbase + (size_t)col*stride + kloc + k16*8;
    GLOAD_LDS16(src, smem + off + wv*1024);
}

__device__ __forceinline__ void mma_chunk(
    const char* smem, int aoff, int boff, int wv, int lane,
    f32x4& acc0, f32x4& acc1)
{
    const int l15 = lane & 15, kch = lane >> 4;
    const int abase = aoff + (wv*16 + l15)*256;
    const int bbase = boff + l15*256;
    const int swz = (l15 & 7) << 4;
    #pragma unroll
    for (int ks = 0; ks < 4; ++ks){
        const int kb = (ks*64 + kch*16) ^ swz;
        bf16x8 a  = *(const bf16x8*)(smem + abase + kb);
        bf16x8 b0 = *(const bf16x8*)(smem + bbase + kb);
        bf16x8 b1 = *(const bf16x8*)(smem + bbase + 4096 + kb);
        acc0 = MFMA(a, b0, acc0);
        acc1 = MFMA(a, b1, acc1);
    }
}

template<class SA, class SB>
__device__ __forceinline__ void gemm_phase(
    char* smem, int wv, int lane, int nc, SA&& sA, SB&& sB,
    f32x4& acc0, f32x4& acc1)
{
    sA(AOFF0, 0); sB(BOFF0, 0);
    asm volatile("s_waitcnt vmcnt(0)" ::: "memory");
    __syncthreads();
    int cur = 0;
    for (int c = 0; c < nc; ++c){
        if (c + 1 < nc){
            sA(cur ? AOFF0 : AOFF1, c+1);
            sB(cur ? BOFF0 : BOFF1, c+1);
        }
        mma_chunk(smem, cur ? AOFF1 : AOFF0, cur ? BOFF1 : BOFF0, wv, lane, acc0, acc1);
        asm volatile("s_waitcnt vmcnt(0)" ::: "memory");
        __syncthreads();
        cur ^= 1;
    }
}

// ---------- prep kernels ----------
__global__ __launch_bounds__(256) void k_tr(
    unsigned short* __restrict__ dst, const float* __restrict__ src,
    int K, int ld, int col_off)
{
    __shared__ float tile[32][33];
    const int kb = blockIdx.x * 32, nb = blockIdx.y * 32;
    const int tx = threadIdx.x & 31, ty = threadIdx.x >> 5;
    #pragma unroll
    for (int i = 0; i < 4; ++i){
        int kl = ty + i*8;
        tile[kl][tx] = src[(size_t)(kb + kl)*ld + col_off + nb + tx];
    }
    __syncthreads();
    #pragma unroll
    for (int i = 0; i < 4; ++i){
        int nl = ty + i*8;
        dst[(size_t)(nb + nl)*K + kb + tx] = f2b(tile[tx][nl]);
    }
}
__global__ __launch_bounds__(256) void k_cvtx(
    const float4* __restrict__ src, ushort4* __restrict__ dst, int n4)
{
    int i = blockIdx.x * 256 + threadIdx.x;
    if (i < n4){
        float4 v = src[i];
        ushort4 o;
        o.x = f2b(v.x); o.y = f2b(v.y); o.z = f2b(v.z); o.w = f2b(v.w);
        dst[i] = o;
    }
}
__global__ __launch_bounds__(256) void k_init(
    const float* __restrict__ x0, const float* __restrict__ s0,
    unsigned short* __restrict__ xbuf_b, float* __restrict__ sb0,
    unsigned short* __restrict__ s_b)
{
    int i = blockIdx.x * 256 + threadIdx.x;
    if (i < B_*OUT_) xbuf_b[i] = f2b(x0[i]);
    if (i < B_*HID_){ sb0[i] = s0[i]; s_b[i] = f2b(s0[i]); }
}

// ================= persistent kernel =================
__global__ __launch_bounds__(512, 1) void k_persist(
    const unsigned short* __restrict__ xb16, const float* __restrict__ xf, int use_xb,
    const unsigned short* __restrict__ Wt,  const unsigned short* __restrict__ Vrt,
    const unsigned short* __restrict__ Vzt, const unsigned short* __restrict__ Vst,
    const unsigned short* __restrict__ Urzt,const unsigned short* __restrict__ Ust,
    const unsigned short* __restrict__ Wxt,
    const float* __restrict__ bias, const float* __restrict__ bx,
    const float* __restrict__ Wy,   const float* __restrict__ by,
    unsigned short* __restrict__ xbuf_b, unsigned short* __restrict__ s_b,
    unsigned short* __restrict__ rs_b,
    float* __restrict__ sb0, float* __restrict__ sb1,
    float* __restrict__ pre, float* __restrict__ logits,
    float* __restrict__ out, unsigned* __restrict__ flags)
{
    __shared__ __align__(16) char smem[81920];
    const int wg   = blockIdx.x;     // 0..95
    const int tid  = threadIdx.x;    // 0..511
    const int lane = tid & 63;
    const int wv   = tid >> 6;       // wave 0..7 (m-tile)
    const int l15  = lane & 15;
    const int kch  = lane >> 4;
    unsigned gen = 0;

    const int n0A   = wg * 32;
    const int nsegA = n0A >> 10;         // 0=r 1=z 2=xs
    const int ncA   = (nsegA == 2) ? 8 : 16;

    for (int t = 0; t < T_; ++t){
        const float* sp = (t & 1) ? sb1 : sb0;
        float*       sn = (t & 1) ? sb0 : sb1;

        // ===== phase A: pre/rs, 96 WGs x 32 cols, K = 2048 (rz) / 1024 (s) =====
        {
            f32x4 acc0 = {0.f,0.f,0.f,0.f}, acc1 = {0.f,0.f,0.f,0.f};
            auto sA = [&](int off, int c){
                const int k0 = c*CK_;
                if (k0 < 512)       stage_act(smem, off, wv, lane, xbuf_b, OUT_, k0);
                else if (k0 < 1024){
                    if (use_xb)     stage_act(smem, off, wv, lane, xb16 + (size_t)t*DIM_, T_*DIM_, k0-512);
                    else            stage_act_f32(smem, off, wv, lane, xf + (size_t)t*DIM_, T_*DIM_, k0-512);
                } else              stage_act(smem, off, wv, lane, s_b, HID_, k0-1024);
            };
            auto sB = [&](int off, int c){
                const int k0 = c*CK_;
                const unsigned short* colbase; int stride, kloc;
                if (k0 < 512){ colbase = Wt + (size_t)n0A*OUT_; stride = OUT_; kloc = k0; }
                else if (k0 < 1024){
                    const unsigned short* Vt = (nsegA==0)?Vrt:((nsegA==1)?Vzt:Vst);
                    colbase = Vt + (size_t)(n0A - (nsegA<<10))*DIM_; stride = DIM_; kloc = k0-512;
                } else { colbase = Urzt + (size_t)n0A*HID_; stride = HID_; kloc = k0-1024; }
                stage_wgt(smem, off, wv, lane, colbase, stride, kloc);
            };
            gemm_phase(smem, wv, lane, ncA, sA, sB, acc0, acc1);

            const int rbase = wv*16 + kch*4;
            #pragma unroll
            for (int half = 0; half < 2; ++half){
                f32x4 acc = half ? acc1 : acc0;
                const int col = n0A + half*16 + l15;
                const float bv = bias[col];
                #pragma unroll
                for (int q = 0; q < 4; ++q){
                    const int r = rbase + q;
                    const float v = acc[q] + bv;
                    if (nsegA == 0){
                        float rs = hardsig(v) * sp[r*HID_ + col];
                        rs_b[r*HID_ + col] = f2b(rs);
                    } else {
                        pre[(size_t)r*K3_ + col] = v;
                    }
                }
            }
        }
        gen++; gsync(flags, gen, wg, tid);

        // ===== phase B: s update, 32 WGs x 32 cols, K = 1024 =====
        if (wg < 32){
            const int n0 = wg * 32;
            f32x4 acc0 = {0.f,0.f,0.f,0.f}, acc1 = {0.f,0.f,0.f,0.f};
            auto sA = [&](int off, int c){ stage_act(smem, off, wv, lane, rs_b, HID_, c*CK_); };
            auto sB = [&](int off, int c){ stage_wgt(smem, off, wv, lane, Ust + (size_t)n0*HID_, HID_, c*CK_); };
            gemm_phase(smem, wv, lane, 8, sA, sB, acc0, acc1);

            const int rbase = wv*16 + kch*4;
            #pragma unroll
            for (int half = 0; half < 2; ++half){
                f32x4 acc = half ? acc1 : acc0;
                const int col = n0 + half*16 + l15;
                #pragma unroll
                for (int q = 0; q < 4; ++q){
                    const int r = rbase + q;
                    float z  = hardsig(pre[(size_t)r*K3_ + HID_ + col]);
                    float xs = pre[(size_t)r*K3_ + 2*HID_ + col];
                    float so = sp[r*HID_ + col];
                    float s1 = tanhf(xs + acc[q]);
                    float snv = (1.f - z)*so + z*s1;
                    sn[r*HID_ + col] = snv;
                    s_b[r*HID_ + col] = f2b(snv);
                }
            }
        }
        gen++; gsync(flags, gen, wg, tid);

        // ===== phase C: logits, 16 WGs x 32 cols, K = 1024 =====
        if (wg < 16){
            const int n0 = wg * 32;
            f32x4 acc0 = {0.f,0.f,0.f,0.f}, acc1 = {0.f,0.f,0.f,0.f};
            auto sA = [&](int off, int c){ stage_act(smem, off, wv, lane, s_b, HID_, c*CK_); };
            auto sB = [&](int off, int c){ stage_wgt(smem, off, wv, lane, Wxt + (size_t)n0*HID_, HID_, c*CK_); };
            gemm_phase(smem, wv, lane, 8, sA, sB, acc0, acc1);

            const int rbase = wv*16 + kch*4;
            #pragma unroll
            for (int half = 0; half < 2; ++half){
                f32x4 acc = half ? acc1 : acc0;
                const int col = n0 + half*16 + l15;
                #pragma unroll
                for (int q = 0; q < 4; ++q){
                    logits[(rbase + q)*OUT_ + col] = acc[q] + bx[col];
                }
            }
        }
        gen++; gsync(flags, gen, wg, tid);

        // ===== phase D: softmax -> x_t ; x_t@Wy -> softmax -> out =====
        {
            float* sm_xs  = (float*)smem;
            float* sm_red = (float*)(smem + 2048);
            for (int r = wg; r < B_; r += NWG_){
                float v = logits[r*OUT_ + tid];
                float m = v;
                #pragma unroll
                for (int off = 32; off > 0; off >>= 1) m = fmaxf(m, __shfl_xor(m, off));
                if (lane == 0) sm_red[wv] = m;
                __syncthreads();
                float mx = sm_red[0];
                #pragma unroll
                for (int q = 1; q < 8; ++q) mx = fmaxf(mx, sm_red[q]);
                float e = expf(v - mx);
                float ssum = e;
                #pragma unroll
                for (int off = 32; off > 0; off >>= 1) ssum += __shfl_xor(ssum, off);
                __syncthreads();
                if (lane == 0) sm_red[wv] = ssum;
                __syncthreads();
                float tot = 0.f;
                #pragma unroll
                for (int q = 0; q < 8; ++q) tot += sm_red[q];
                float xv = e / tot;
                sm_xs[tid] = xv;
                xbuf_b[r*OUT_ + tid] = f2b(xv);
                __syncthreads();
                const int tag = tid & 63, part = tid >> 6;
                float p = 0.f;
                const int k0 = part * 64;
                #pragma unroll 4
                for (int k = k0; k < k0 + 64; ++k) p += sm_xs[k] * Wy[k*TAG_ + tag];
                sm_red[tid] = p;
                __syncthreads();
                if (tid < 64){
                    float tl = by[tid];
                    #pragma unroll
                    for (int q = 0; q < 8; ++q) tl += sm_red[q*64 + tid];
                    float wm = tl;
                    #pragma unroll
                    for (int off = 32; off > 0; off >>= 1) wm = fmaxf(wm, __shfl_xor(wm, off));
                    float ex = expf(tl - wm);
                    float sm = ex;
                    #pragma unroll
                    for (int off = 32; off > 0; off >>= 1) sm += __shfl_xor(sm, off);
                    out[((long)r*T_ + t)*TAG_ + tid] = ex / sm;
                }
                __syncthreads();
            }
        }
        gen++; gsync(flags, gen, wg, tid);
    }
}

extern "C" void kernel_launch(void* const* d_in, const int* in_sizes, int n_in,
                              void* d_out, int out_size, void* d_ws, size_t ws_size,
                              hipStream_t stream){
    const float* x   = (const float*)d_in[0];
    const float* x0  = (const float*)d_in[1];
    const float* s0  = (const float*)d_in[2];
    const float* W   = (const float*)d_in[3];
    const float* U   = (const float*)d_in[4];
    const float* b   = (const float*)d_in[5];
    const float* Wx  = (const float*)d_in[6];
    const float* bx  = (const float*)d_in[7];
    const float* Vr  = (const float*)d_in[8];
    const float* Vz  = (const float*)d_in[9];
    const float* Vs  = (const float*)d_in[10];
    const float* Wy  = (const float*)d_in[11];
    const float* by  = (const float*)d_in[12];
    float* out = (float*)d_out;

    char* ws = (char*)d_ws;
    size_t off = 0;
    auto alloc = [&](size_t bytes) -> size_t {
        size_t o = off; off = (off + bytes + 255) & ~(size_t)255; return o;
    };
    unsigned* flags       = (unsigned*)(ws + alloc(512));
    unsigned short* Wt    = (unsigned short*)(ws + alloc((size_t)K3_*OUT_*2));
    unsigned short* Urzt  = (unsigned short*)(ws + alloc((size_t)2048*HID_*2));
    unsigned short* Ust   = (unsigned short*)(ws + alloc((size_t)HID_*HID_*2));
    unsigned short* Vrt   = (unsigned short*)(ws + alloc((size_t)HID_*DIM_*2));
    unsigned short* Vzt   = (unsigned short*)(ws + alloc((size_t)HID_*DIM_*2));
    unsigned short* Vst   = (unsigned short*)(ws + alloc((size_t)HID_*DIM_*2));
    unsigned short* Wxt   = (unsigned short*)(ws + alloc((size_t)OUT_*HID_*2));
    unsigned short* xbuf_b= (unsigned short*)(ws + alloc((size_t)B_*OUT_*2));
    unsigned short* s_b   = (unsigned short*)(ws + alloc((size_t)B_*HID_*2));
    unsigned short* rs_b  = (unsigned short*)(ws + alloc((size_t)B_*HID_*2));
    float* sb0    = (float*)(ws + alloc((size_t)B_*HID_*4));
    float* sb1    = (float*)(ws + alloc((size_t)B_*HID_*4));
    float* pre    = (float*)(ws + alloc((size_t)B_*K3_*4));
    float* logits = (float*)(ws + alloc((size_t)B_*OUT_*4));
    unsigned short* xb16 = (unsigned short*)(ws + alloc((size_t)B_*T_*DIM_*2));
    int use_xb = (off <= ws_size) ? 1 : 0;

    hipMemsetAsync(flags, 0, 512, stream);
    k_tr<<<dim3(OUT_/32, K3_/32),  256, 0, stream>>>(Wt,   W,  OUT_, K3_, 0);
    k_tr<<<dim3(HID_/32, 2048/32), 256, 0, stream>>>(Urzt, U,  HID_, K3_, 0);
    k_tr<<<dim3(HID_/32, HID_/32), 256, 0, stream>>>(Ust,  U,  HID_, K3_, 2048);
    k_tr<<<dim3(DIM_/32, HID_/32), 256, 0, stream>>>(Vrt,  Vr, DIM_, HID_, 0);
    k_tr<<<dim3(DIM_/32, HID_/32), 256, 0, stream>>>(Vzt,  Vz, DIM_, HID_, 0);
    k_tr<<<dim3(DIM_/32, HID_/32), 256, 0, stream>>>(Vst,  Vs, DIM_, HID_, 0);
    k_tr<<<dim3(HID_/32, OUT_/32), 256, 0, stream>>>(Wxt,  Wx, HID_, OUT_, 0);
    if (use_xb){
        int n4 = B_*T_*DIM_/4;
        k_cvtx<<<(n4 + 255)/256, 256, 0, stream>>>((const float4*)x, (ushort4*)xb16, n4);
    }
    k_init<<<(B_*HID_ + 255)/256, 256, 0, stream>>>(x0, s0, xbuf_b, sb0, s_b);

    const unsigned short* xb16c = xb16;
    void* kargs[] = {
        (void*)&xb16c, (void*)&x, (void*)&use_xb,
        (void*)&Wt, (void*)&Vrt, (void*)&Vzt, (void*)&Vst, (void*)&Urzt, (void*)&Ust,
        (void*)&Wxt, (void*)&b, (void*)&bx, (void*)&Wy, (void*)&by,
        (void*)&xbuf_b, (void*)&s_b, (void*)&rs_b,
        (void*)&sb0, (void*)&sb1, (void*)&pre, (void*)&logits,
        (void*)&out, (void*)&flags
    };
    hipError_t err = hipLaunchCooperativeKernel((const void*)k_persist,
                                                dim3(NWG_), dim3(512),
                                                kargs, 0, stream);
    if (err != hipSuccess){
        // 96 WGs with 80KB LDS -> 1 WG/CU, 96 < 256 CUs: co-residency by capacity.
        k_persist<<<NWG_, 512, 0, stream>>>(
            xb16c, x, use_xb, Wt, Vrt, Vzt, Vst, Urzt, Ust, Wxt,
            b, bx, Wy, by, xbuf_b, s_b, rs_b, sb0, sb1, pre, logits, out, flags);
    }
}